// Round 1
// baseline (125.168 us; speedup 1.0000x reference)
//
#include <hip/hip_runtime.h>
#include <hip/hip_bf16.h>

#define NN 8192
#define DD 256
#define BB 4096
#define CSPLIT 16
#define COLS_PER_SPLIT (NN / CSPLIT)   // 512
#define COLTILE 64
#define TEMP_SCALE 2.0f                // 1/TEMPERATURE

typedef __attribute__((ext_vector_type(8))) short short8;
typedef __attribute__((ext_vector_type(4))) float f32x4;

static __device__ inline ushort f2bf(float x) {
    __hip_bfloat16 h = __float2bfloat16(x);
    return *reinterpret_cast<ushort*>(&h);
}

// Kernel 1: L2-normalize rows of concat(z_i, z_j) -> bf16 zn[8192][256]
__global__ __launch_bounds__(256) void norm_kernel(const float* __restrict__ zi,
                                                   const float* __restrict__ zj,
                                                   ushort* __restrict__ zn) {
    int row  = (blockIdx.x * 256 + threadIdx.x) >> 6;
    int lane = threadIdx.x & 63;
    if (row >= NN) return;
    const float* src = (row < BB) ? (zi + (size_t)row * DD)
                                  : (zj + (size_t)(row - BB) * DD);
    float4 v = ((const float4*)src)[lane];
    float ss = v.x * v.x + v.y * v.y + v.z * v.z + v.w * v.w;
    #pragma unroll
    for (int m = 32; m; m >>= 1) ss += __shfl_xor(ss, m, 64);
    float inv = 1.0f / fmaxf(sqrtf(ss), 1e-8f);
    ushort4 o;
    o.x = f2bf(v.x * inv);
    o.y = f2bf(v.y * inv);
    o.z = f2bf(v.z * inv);
    o.w = f2bf(v.w * inv);
    ((ushort4*)(zn + (size_t)row * DD))[lane] = o;
}

// Kernel 2: fused sim tile + sum-of-exp per row (no max needed: |s| <= 2)
// grid: (32 row-blocks, 16 col-splits), 256 threads (4 waves x 64 rows).
__global__ __launch_bounds__(256, 2) void sim_kernel(const ushort* __restrict__ zn,
                                                     float* __restrict__ psum,
                                                     float* __restrict__ pos) {
    __shared__ int4 lds4[COLTILE * 32];   // 64 cols x 256 bf16 = 32 KB, XOR-swizzled granules

    const int tid  = threadIdx.x;
    const int wid  = tid >> 6;
    const int lane = tid & 63;
    const int l15  = lane & 15;
    const int lhi  = lane >> 4;

    const int row0     = blockIdx.x * 256 + wid * 64;   // this wave's 64 rows
    const int colbase0 = blockIdx.y * COLS_PER_SPLIT;

    // A fragments: 4 row-subtiles x 8 k-steps, held in registers all loop (128 VGPR)
    short8 a[4][8];
    #pragma unroll
    for (int rt = 0; rt < 4; ++rt)
        #pragma unroll
        for (int kk = 0; kk < 8; ++kk) {
            const ushort* p = zn + (size_t)(row0 + rt * 16 + l15) * DD + kk * 32 + lhi * 8;
            a[rt][kk] = *(const short8*)p;
        }

    f32x4 sume[4];
    #pragma unroll
    for (int rt = 0; rt < 4; ++rt) sume[rt] = (f32x4){0.f, 0.f, 0.f, 0.f};

    for (int ct = 0; ct < COLS_PER_SPLIT; ct += COLTILE) {
        const int colb = colbase0 + ct;
        __syncthreads();
        // stage 64 zn rows (= sim columns) into LDS; granule g = 16B chunk.
        // swizzle: granule-col ^= (row & 7)  (flips byte-addr bits 4..6)
        #pragma unroll
        for (int i = 0; i < 8; ++i) {
            int g   = tid + i * 256;       // 0..2047
            int r   = g >> 5;              // staged row 0..63
            int c16 = g & 31;              // granule within row
            int4 v = *(const int4*)(zn + (size_t)(colb + r) * DD + c16 * 8);
            lds4[r * 32 + (c16 ^ (r & 7))] = v;
        }
        __syncthreads();

        #pragma unroll
        for (int sub = 0; sub < 4; ++sub) {
            const int brow = sub * 16 + l15;         // staged column index (B-frag "col")
            short8 b[8];
            #pragma unroll
            for (int kk = 0; kk < 8; ++kk) {
                int gidx = brow * 32 + ((kk * 4 + lhi) ^ (brow & 7));
                b[kk] = ((const short8*)lds4)[gidx];
            }
            const int gc = colb + brow;              // global column; D-layout col = lane&15 ✓
            #pragma unroll
            for (int rt = 0; rt < 4; ++rt) {
                f32x4 acc = (f32x4){0.f, 0.f, 0.f, 0.f};
                #pragma unroll
                for (int kk = 0; kk < 8; ++kk)
                    acc = __builtin_amdgcn_mfma_f32_16x16x32_bf16(a[rt][kk], b[kk], acc, 0, 0, 0);
                #pragma unroll
                for (int reg = 0; reg < 4; ++reg) {
                    int gr  = row0 + rt * 16 + lhi * 4 + reg;   // D-layout row
                    float s = acc[reg] * TEMP_SCALE;
                    float e = (gc == gr) ? 0.0f : __expf(s);    // mask self-diagonal
                    sume[rt][reg] += e;
                    if (gc == (gr ^ BB)) pos[gr] = s;           // positive pair
                }
            }
        }
    }

    // reduce sum-of-exp across the 16 lanes of each row group, write partials
    #pragma unroll
    for (int rt = 0; rt < 4; ++rt) {
        #pragma unroll
        for (int reg = 0; reg < 4; ++reg) {
            float v = sume[rt][reg];
            v += __shfl_xor(v, 1, 64);
            v += __shfl_xor(v, 2, 64);
            v += __shfl_xor(v, 4, 64);
            v += __shfl_xor(v, 8, 64);
            if (l15 == 0) {
                int gr = row0 + rt * 16 + lhi * 4 + reg;
                psum[(size_t)blockIdx.y * NN + gr] = v;
            }
        }
    }
}

// Kernel 3a: per-row lse - pos, block partial sums
__global__ __launch_bounds__(256) void reduce1(const float* __restrict__ psum,
                                               const float* __restrict__ pos,
                                               float* __restrict__ partial) {
    int r    = blockIdx.x * 256 + threadIdx.x;
    int lane = threadIdx.x & 63;
    int wid  = threadIdx.x >> 6;
    float sum = 0.f;
    #pragma unroll
    for (int s = 0; s < CSPLIT; ++s) sum += psum[(size_t)s * NN + r];
    float v = logf(sum) - pos[r];
    #pragma unroll
    for (int m = 32; m; m >>= 1) v += __shfl_xor(v, m, 64);
    __shared__ float red[4];
    if (lane == 0) red[wid] = v;
    __syncthreads();
    if (threadIdx.x == 0) partial[blockIdx.x] = red[0] + red[1] + red[2] + red[3];
}

// Kernel 3b: final mean
__global__ void reduce2(const float* __restrict__ partial, float* __restrict__ out) {
    int lane = threadIdx.x & 63;
    float v = (lane < 32) ? partial[lane] : 0.f;
    #pragma unroll
    for (int m = 32; m; m >>= 1) v += __shfl_xor(v, m, 64);
    if (lane == 0) out[0] = v * (1.0f / NN);
}

extern "C" void kernel_launch(void* const* d_in, const int* in_sizes, int n_in,
                              void* d_out, int out_size, void* d_ws, size_t ws_size,
                              hipStream_t stream) {
    const float* zi = (const float*)d_in[0];
    const float* zj = (const float*)d_in[1];
    float* out = (float*)d_out;

    char* ws = (char*)d_ws;
    ushort* zn     = (ushort*)ws;                                   // 8192*256*2 = 4 MB
    size_t  off    = (size_t)NN * DD * 2;
    float*  psum   = (float*)(ws + off);  off += (size_t)CSPLIT * NN * 4;  // 512 KB
    float*  pos    = (float*)(ws + off);  off += (size_t)NN * 4;           // 32 KB
    float*  partial= (float*)(ws + off);                                   // 128 B

    norm_kernel<<<NN / 4, 256, 0, stream>>>(zi, zj, zn);
    dim3 g2(NN / 256, CSPLIT);
    sim_kernel<<<g2, 256, 0, stream>>>(zn, psum, pos);
    reduce1<<<NN / 256, 256, 0, stream>>>(psum, pos, partial);
    reduce2<<<1, 64, 0, stream>>>(partial, out);
}